// Round 1
// 5112.282 us; speedup vs baseline: 1.0237x; 1.0237x over previous
//
#include <hip/hip_runtime.h>
#include <stdint.h>

typedef __attribute__((ext_vector_type(8))) short short8;
typedef __attribute__((ext_vector_type(4))) float f32x4;

// ---- workspace byte offsets (total ~141.8 MB) ----
#define XB16_OFF  0UL           // bf16 layer input/output [t*64+b][512]   32 MB
#define XP_OFF    33554432UL    // fp16 projections, gru-native layout     96 MB
#define WT_OFF    134217728UL   // bf16 W^T  [3][1536][512]               4.5 MB
#define UT_OFF    138936320UL   // bf16 U^T  [dir*3+l][768][256]         2.25 MB
#define BIASC_OFF 141295616UL   // fp32 input bias (+recur bias for z,r) [3][1536]
#define BRC_OFF   141314048UL   // fp32 recur bias [dir*3+l][768]
#define MASKT_OFF 141332480UL   // byte mask transposed [t][64]           32 KB
#define FLAG_OFF  141725760UL   // mask-dtype flag

#define HB_STRIDE 264           // 256 + 8 pad halves (conflict-free b128 reads)

// ---- threefry2x32, 20 rounds (jax partitionable mode) ----
__host__ __device__ static inline void tf2x32(unsigned k0, unsigned k1,
                                              unsigned x0, unsigned x1,
                                              unsigned* o0, unsigned* o1) {
  unsigned ks2 = k0 ^ k1 ^ 0x1BD11BDAu;
#define TFR(r) { x0 += x1; x1 = (x1 << (r)) | (x1 >> (32 - (r))); x1 ^= x0; }
  x0 += k0; x1 += k1;
  TFR(13) TFR(15) TFR(26) TFR(6)   x0 += k1;  x1 += ks2 + 1u;
  TFR(17) TFR(29) TFR(16) TFR(24)  x0 += ks2; x1 += k0 + 2u;
  TFR(13) TFR(15) TFR(26) TFR(6)   x0 += k0;  x1 += k1 + 3u;
  TFR(17) TFR(29) TFR(16) TFR(24)  x0 += k1;  x1 += ks2 + 4u;
  TFR(13) TFR(15) TFR(26) TFR(6)   x0 += ks2; x1 += k0 + 5u;
#undef TFR
  *o0 = x0; *o1 = x1;
}

__device__ static inline short f2bf(float f) {  // RNE fp32->bf16
  unsigned u = __float_as_uint(f);
  u = (u + 0x7fffu + ((u >> 16) & 1u)) >> 16;
  return (short)u;
}
__device__ static inline float bf2f(short s) {
  unsigned u = ((unsigned)(unsigned short)s) << 16;
  return __uint_as_float(u);
}
__device__ static inline float cvt_lo(unsigned d) {
  union { unsigned short u; _Float16 h; } c; c.u = (unsigned short)(d & 0xffffu);
  return (float)c.h;
}
__device__ static inline float cvt_hi(unsigned d) {
  union { unsigned short u; _Float16 h; } c; c.u = (unsigned short)(d >> 16);
  return (float)c.h;
}

__global__ void init_k(unsigned* flag) {
  if (threadIdx.x == 0) *flag = 0u;
}

// ---- prep: casts, transposes, tail copy, mask dtype detection ----
__global__ __launch_bounds__(256) void prep_k(
    const float* __restrict__ states, const unsigned* __restrict__ maskw,
    const float* __restrict__ Wf, const float* __restrict__ Uf,
    const float* __restrict__ bf_, const float* __restrict__ Wb,
    const float* __restrict__ Ub, const float* __restrict__ bb_,
    short* __restrict__ xb16, float* __restrict__ dout,
    short* __restrict__ Wt, short* __restrict__ Ut,
    float* __restrict__ biasc, float* __restrict__ brc,
    unsigned* __restrict__ flag) {
  const unsigned gid = blockIdx.x * 256 + threadIdx.x;  // 16,777,216 threads
  {  // states [b*512+t][512] -> xb16 t-major [t*64+b][512]
    unsigned c = gid & 511u, rw = gid >> 9;
    unsigned t = rw >> 6, b = rw & 63u;
    xb16[gid] = f2bf(states[(size_t)(b * 512 + t) * 512 + c]);
  }
  if (gid < 512000u) dout[16777216u + gid] = states[16777216u + gid];  // EXTRA tail
  if (gid < 2359296u) {  // W^T bf16: [l][n(1536)][k(512)]
    unsigned l = gid / 786432u, rem = gid % 786432u;
    unsigned n = rem >> 9, k = rem & 511u;
    float s = (n < 768u) ? Wf[(size_t)(l * 512 + k) * 768 + n]
                         : Wb[(size_t)(l * 512 + k) * 768 + (n - 768u)];
    Wt[gid] = f2bf(s);
  }
  if (gid < 1179648u) {  // U^T bf16: [(dir*3+l)][n(768)][k(256)]
    unsigned g = gid / 196608u, rem = gid % 196608u;
    unsigned dirv = g / 3u, l = g % 3u;
    unsigned n = rem >> 8, k = rem & 255u;
    const float* Usrc = dirv ? Ub : Uf;
    Ut[gid] = f2bf(Usrc[(size_t)(l * 256 + k) * 768 + n]);
  }
  if (gid < 4608u) {  // input bias concat [l][1536]; fold recur bias for z,r gates
    unsigned l = gid / 1536u, n = gid % 1536u;
    unsigned dirv = n / 768u, rem = n % 768u;
    const float* bsrc = dirv ? bb_ : bf_;
    float v = bsrc[(l * 2 + 0) * 768 + rem];
    if (rem < 512u) v += bsrc[(l * 2 + 1) * 768 + rem];   // z,r: additive -> fold
    biasc[gid] = v;
  }
  if (gid < 4608u) {  // recurrent bias [(dir*3+l)][768] (h-gate part used by gru)
    unsigned g = gid / 768u, n = gid % 768u;
    unsigned dirv = g / 3u, l = g % 3u;
    brc[gid] = (dirv ? bb_ : bf_)[(l * 2 + 1) * 768 + n];
  }
  if (gid < 8192u) {  // mask stored as bytes? any word >1 => yes
    if (maskw[gid] > 1u) atomicOr(flag, 1u);
  }
}

// ---- mask transpose: [b][t] (byte or word) -> bytes [t][64] ----
__global__ __launch_bounds__(256) void maskt_k(
    const unsigned char* __restrict__ mask8, const unsigned* __restrict__ flagp,
    unsigned char* __restrict__ maskt) {
  const unsigned gid = blockIdx.x * 256 + threadIdx.x;  // 32768
  const unsigned b = gid >> 9, t = gid & 511u;
  const bool mbyte = (*flagp) != 0u;
  unsigned v = mbyte ? (unsigned)mask8[gid] : ((const unsigned*)mask8)[gid];
  maskt[t * 64 + b] = v ? 1u : 0u;
}

// ---- projection GEMM: [32768,512]bf16 x [512,1536]bf16 -> fp16 + bias ----
// Output layout is gru-native: row*1536 + dir*768 + w*96 + col*6 + gate*2 + g
__global__ __launch_bounds__(256) void proj_gemm(
    const short* __restrict__ A, const short* __restrict__ Bt,
    const float* __restrict__ bias, _Float16* __restrict__ C) {
  __shared__ __align__(16) short As[4096];
  __shared__ __align__(16) short Bs[4096];
  const int tid = threadIdx.x;
  const int wave = tid >> 6, lane = tid & 63;
  const int col = lane & 15, kq = lane >> 4;
  const int wr = wave >> 1, wc = wave & 1;
  const int m0 = blockIdx.x * 128, n0 = blockIdx.y * 128;
  const uint4* Aq = (const uint4*)A;
  const uint4* Bq = (const uint4*)Bt;
  uint4* AsQ = (uint4*)As;
  uint4* BsQ = (uint4*)Bs;
  f32x4 acc[4][4];
#pragma unroll
  for (int i = 0; i < 4; ++i)
#pragma unroll
    for (int j = 0; j < 4; ++j) acc[i][j] = (f32x4){0.f, 0.f, 0.f, 0.f};

  for (int kt = 0; kt < 16; ++kt) {
    const int k8 = kt * 4;
#pragma unroll
    for (int rnd = 0; rnd < 2; ++rnd) {
      int chunk = rnd * 256 + tid;
      int row = chunk >> 2, kc = chunk & 3;
      AsQ[chunk] = Aq[(size_t)(m0 + row) * 64 + k8 + kc];
      BsQ[chunk] = Bq[(size_t)(n0 + row) * 64 + k8 + kc];
    }
    __syncthreads();
    short8 af[4], bfv[4];
#pragma unroll
    for (int i = 0; i < 4; ++i)
      af[i] = *(const short8*)(As + (wr * 64 + i * 16 + col) * 32 + kq * 8);
#pragma unroll
    for (int j = 0; j < 4; ++j)
      bfv[j] = *(const short8*)(Bs + (wc * 64 + j * 16 + col) * 32 + kq * 8);
#pragma unroll
    for (int i = 0; i < 4; ++i)
#pragma unroll
      for (int j = 0; j < 4; ++j)
        acc[i][j] = __builtin_amdgcn_mfma_f32_16x16x32_bf16(af[i], bfv[j], acc[i][j], 0, 0, 0);
    __syncthreads();
  }
#pragma unroll
  for (int j = 0; j < 4; ++j) {
    const int cg = n0 + wc * 64 + j * 16 + col;
    const float bv = bias[cg];
    const int dirv = cg / 768, rem = cg % 768;
    const int gate = rem >> 8, u = rem & 255;
    const int colofs = dirv * 768 + (u >> 5) * 96 + (u & 15) * 6 + gate * 2 + ((u >> 4) & 1);
#pragma unroll
    for (int i = 0; i < 4; ++i) {
      const int rb = m0 + wr * 64 + i * 16 + kq * 4;
#pragma unroll
      for (int r = 0; r < 4; ++r)
        C[(size_t)(rb + r) * 1536 + colofs] = (_Float16)(acc[i][j][r] + bv);
    }
  }
}

// ---- register-resident recurrent kernel: grid = 8 (2 dir x 4 batch slices) ----
// All 3 gates' U^T fragments live in the unified VGPR/AGPR file (48 short8).
// LDS holds only the 16-row h double-buffer. 8 ds_read_b128/thread/step.
__global__ __launch_bounds__(512, 2) void gru_reg(
    const _Float16* __restrict__ xp, const short* __restrict__ UtAll,
    const float* __restrict__ brcAll, const unsigned char* __restrict__ maskt,
    short* __restrict__ yout, int layer) {
  __shared__ short hbuf[2][16][HB_STRIDE];   // 16.9 KB
  const int bid = blockIdx.x;
  const int dir = bid >> 2;
  const int b0 = (bid & 3) * 16;
  const int tid = threadIdx.x;
  const int wave = tid >> 6, lane = tid & 63;
  const int col = lane & 15, quad = lane >> 4;
  const short* Ut = UtAll + (size_t)(dir * 3 + layer) * 768 * 256;
  const float* brc = brcAll + (dir * 3 + layer) * 768;

  short* hb_flat = &hbuf[0][0][0];
  for (int i = tid; i < 2 * 16 * HB_STRIDE; i += 512) hb_flat[i] = 0;

  // resident U^T fragments for z, r, h gates (lane holds B[k=quad*8+j][n=u])
  short8 zB[2][8], rB[2][8], hB[2][8];
  float brh[2];
#pragma unroll
  for (int g = 0; g < 2; ++g) {
    const int u = wave * 32 + g * 16 + col;
#pragma unroll
    for (int ks = 0; ks < 8; ++ks) {
      zB[g][ks] = *(const short8*)(Ut + (size_t)u * 256 + ks * 32 + quad * 8);
      rB[g][ks] = *(const short8*)(Ut + (size_t)(256 + u) * 256 + ks * 32 + quad * 8);
      hB[g][ks] = *(const short8*)(Ut + (size_t)(512 + u) * 256 + ks * 32 + quad * 8);
    }
    brh[g] = brc[512 + u];
  }

  // xp addressing: byte offset = (t*64+b)*3072 + dir*1536 + wave*192 + col*12
  const int t0 = dir ? 511 : 0;
  const int tstep = dir ? -1 : 1;
  const int xstep = tstep * 64 * 3072;
  const char* xpb = (const char*)xp;
  unsigned xoff[4];
#pragma unroll
  for (int r = 0; r < 4; ++r)
    xoff[r] = (unsigned)((t0 * 64 + b0 + quad * 4 + r) * 3072 +
                         dir * 1536 + wave * 192 + col * 12);

  // precomputed lane offsets into hbuf (halves)
  const int rd_lane = col * HB_STRIDE + quad * 8;
  const int wr_lane = (quad * 4) * HB_STRIDE + wave * 32 + col;
  const size_t yt_lane = (size_t)(b0 + quad * 4) * 512 + dir * 256 + wave * 32 + col;

  // prologue prefetch for s=0
  unsigned pz[4], pr[4], phc[4], pmc;
#pragma unroll
  for (int r = 0; r < 4; ++r) {
    pz[r]  = *(const unsigned*)(xpb + xoff[r]);
    pr[r]  = *(const unsigned*)(xpb + xoff[r] + 4);
    phc[r] = *(const unsigned*)(xpb + xoff[r] + 8);
  }
  pmc = *(const unsigned*)(maskt + t0 * 64 + b0 + quad * 4);

  float hp[2][4] = {{0.f, 0.f, 0.f, 0.f}, {0.f, 0.f, 0.f, 0.f}};
  __syncthreads();

  for (int s = 0; s < 512; ++s) {
    const int t = t0 + tstep * s;
    // init accumulators from prefetched projections (z,r) and recur bias (h)
    f32x4 az[2], ar[2], ah[2];
#pragma unroll
    for (int r = 0; r < 4; ++r) {
      az[0][r] = cvt_lo(pz[r]); az[1][r] = cvt_hi(pz[r]);
      ar[0][r] = cvt_lo(pr[r]); ar[1][r] = cvt_hi(pr[r]);
      ah[0][r] = brh[0];        ah[1][r] = brh[1];
    }
    // issue next-step z/r prefetch (consumed at next init)
    if (s < 511) {
#pragma unroll
      for (int r = 0; r < 4; ++r) {
        xoff[r] += xstep;
        pz[r] = *(const unsigned*)(xpb + xoff[r]);
        pr[r] = *(const unsigned*)(xpb + xoff[r] + 4);
      }
    }

    // recurrent matmul: h(t-1) @ U^T for all 3 gates
    const short* hrd = hb_flat + (s & 1) * (16 * HB_STRIDE) + rd_lane;
#pragma unroll
    for (int ks = 0; ks < 8; ++ks) {
      short8 a = *(const short8*)(hrd + ks * 32);
      az[0] = __builtin_amdgcn_mfma_f32_16x16x32_bf16(a, zB[0][ks], az[0], 0, 0, 0);
      az[1] = __builtin_amdgcn_mfma_f32_16x16x32_bf16(a, zB[1][ks], az[1], 0, 0, 0);
      ar[0] = __builtin_amdgcn_mfma_f32_16x16x32_bf16(a, rB[0][ks], ar[0], 0, 0, 0);
      ar[1] = __builtin_amdgcn_mfma_f32_16x16x32_bf16(a, rB[1][ks], ar[1], 0, 0, 0);
      ah[0] = __builtin_amdgcn_mfma_f32_16x16x32_bf16(a, hB[0][ks], ah[0], 0, 0, 0);
      ah[1] = __builtin_amdgcn_mfma_f32_16x16x32_bf16(a, hB[1][ks], ah[1], 0, 0, 0);
    }

    // epilogue
    short* hwr = hb_flat + ((s & 1) ^ 1) * (16 * HB_STRIDE) + wr_lane;
    short* yt = yout + (size_t)t * 32768 + yt_lane;
    bool mb[4];
#pragma unroll
    for (int r = 0; r < 4; ++r) mb[r] = ((pmc >> (8 * r)) & 0xffu) != 0u;
#pragma unroll
    for (int g = 0; g < 2; ++g) {
#pragma unroll
      for (int r = 0; r < 4; ++r) {
        float z  = 1.f / (1.f + __expf(-az[g][r]));
        float rr = 1.f / (1.f + __expf(-ar[g][r]));
        float xh = g ? cvt_hi(phc[r]) : cvt_lo(phc[r]);
        float pre = xh + rr * ah[g][r];
        float hc = 1.f - 2.f / (__expf(2.f * pre) + 1.f);
        float hpv = hp[g][r];
        float hn = hc + z * (hpv - hc);
        hn = mb[r] ? hn : hpv;
        hp[g][r] = hn;
        short hnb = f2bf(hn);
        hwr[r * HB_STRIDE + g * 16] = hnb;
        yt[r * 512 + g * 16] = hnb;
      }
    }
    // issue next-step h/mask prefetch (consumed at next epilogue)
    if (s < 511) {
#pragma unroll
      for (int r = 0; r < 4; ++r)
        phc[r] = *(const unsigned*)(xpb + xoff[r] + 8);
      pmc = *(const unsigned*)(maskt + (t + tstep) * 64 + b0 + quad * 4);
    }
    __syncthreads();
  }
}

// ---- dropout (JAX threefry partitionable); j == gid (t-major) ----
__global__ __launch_bounds__(256) void drop_k(
    short* __restrict__ xb16, float* __restrict__ dout,
    const int* __restrict__ training, unsigned k0, unsigned k1, int last) {
  const unsigned gid = blockIdx.x * 256 + threadIdx.x;
  float v = bf2f(xb16[gid]);
  unsigned y0, y1;
  tf2x32(k0, k1, 0u, gid, &y0, &y1);
  unsigned bits = y0 ^ y1;
  float u = __uint_as_float((bits >> 9) | 0x3f800000u) - 1.0f;
  bool keep = u < 0.9f;
  int tr = *training;
  float ov = tr ? (keep ? v * (1.0f / 0.9f) : 0.0f) : v;
  if (last) {
    unsigned r = gid >> 9, c = gid & 511u;
    unsigned t = r >> 6, b = r & 63u;
    dout[(size_t)(b * 512 + t) * 512 + c] = ov;
  } else {
    xb16[gid] = f2bf(ov);
  }
}

extern "C" void kernel_launch(void* const* d_in, const int* in_sizes, int n_in,
                              void* d_out, int out_size, void* d_ws, size_t ws_size,
                              hipStream_t stream) {
  (void)in_sizes; (void)n_in; (void)out_size; (void)ws_size;
  const float* states = (const float*)d_in[0];
  const void*  mask   = d_in[1];
  const int*   training = (const int*)d_in[3];
  const float* Wf = (const float*)d_in[4];
  const float* Uf = (const float*)d_in[5];
  const float* bf_ = (const float*)d_in[6];
  const float* Wb = (const float*)d_in[7];
  const float* Ub = (const float*)d_in[8];
  const float* bb_ = (const float*)d_in[9];
  char* ws = (char*)d_ws;

  short* xb16   = (short*)(ws + XB16_OFF);
  _Float16* xp  = (_Float16*)(ws + XP_OFF);
  short* Wt     = (short*)(ws + WT_OFF);
  short* Ut     = (short*)(ws + UT_OFF);
  float* biasc  = (float*)(ws + BIASC_OFF);
  float* brc    = (float*)(ws + BRC_OFF);
  unsigned char* maskt = (unsigned char*)(ws + MASKT_OFF);
  unsigned* flag = (unsigned*)(ws + FLAG_OFF);
  float* dout = (float*)d_out;

  // threefry key chain: key(1234); per layer: dkey,sk = split(dkey)
  unsigned d0 = 0u, d1 = 1234u, sk0[3], sk1[3];
  for (int l = 0; l < 3; ++l) {
    unsigned a, b, c, d;
    tf2x32(d0, d1, 0u, 0u, &a, &b);   // new dkey
    tf2x32(d0, d1, 0u, 1u, &c, &d);   // subkey
    sk0[l] = c; sk1[l] = d;
    d0 = a; d1 = b;
  }

  init_k<<<1, 64, 0, stream>>>(flag);
  prep_k<<<65536, 256, 0, stream>>>(states, (const unsigned*)mask, Wf, Uf, bf_,
                                    Wb, Ub, bb_, xb16, dout, Wt, Ut, biasc, brc, flag);
  maskt_k<<<128, 256, 0, stream>>>((const unsigned char*)mask, flag, maskt);
  for (int l = 0; l < 3; ++l) {
    proj_gemm<<<dim3(256, 12), 256, 0, stream>>>(xb16, Wt + (size_t)l * 1536 * 512,
                                                 biasc + l * 1536, xp);
    gru_reg<<<8, 512, 0, stream>>>(xp, Ut, brc, maskt, xb16, l);
    drop_k<<<65536, 256, 0, stream>>>(xb16, dout, training, sk0[l], sk1[l], l == 2);
  }
}

// Round 2
// 4200.056 us; speedup vs baseline: 1.2460x; 1.2172x over previous
//
#include <hip/hip_runtime.h>
#include <stdint.h>

typedef __attribute__((ext_vector_type(8))) short short8;
typedef __attribute__((ext_vector_type(4))) float f32x4;

// ---- workspace byte offsets (total ~141.8 MB) ----
#define XB16_OFF  0UL           // bf16 layer input/output [t*64+b][512]   32 MB
#define XP_OFF    33554432UL    // fp16 projections, gru-native layout     96 MB
#define WT_OFF    134217728UL   // bf16 W^T  [3][1536][512]               4.5 MB
#define UT_OFF    138936320UL   // bf16 U^T  [dir*3+l][768][256]         2.25 MB
#define BIASC_OFF 141295616UL   // fp32 input bias (+recur bias for z,r) [3][1536]
#define BRC_OFF   141314048UL   // fp32 recur bias [dir*3+l][768]
#define MASKT_OFF 141332480UL   // byte mask transposed [t][64]           32 KB
#define FLAG_OFF  141725760UL   // mask-dtype flag

#define HB_STRIDE 264           // 256 + 8 pad halves (conflict-free b128 reads)
#define HBLK (16 * HB_STRIDE)
// LDS: h-gate U^T [256][HB_STRIDE] + h state double buffer [2][16][HB_STRIDE]
#define LDS_BYTES (((size_t)256 * HB_STRIDE + 2 * HBLK) * 2)

// ---- threefry2x32, 20 rounds (jax partitionable mode) ----
__host__ __device__ static inline void tf2x32(unsigned k0, unsigned k1,
                                              unsigned x0, unsigned x1,
                                              unsigned* o0, unsigned* o1) {
  unsigned ks2 = k0 ^ k1 ^ 0x1BD11BDAu;
#define TFR(r) { x0 += x1; x1 = (x1 << (r)) | (x1 >> (32 - (r))); x1 ^= x0; }
  x0 += k0; x1 += k1;
  TFR(13) TFR(15) TFR(26) TFR(6)   x0 += k1;  x1 += ks2 + 1u;
  TFR(17) TFR(29) TFR(16) TFR(24)  x0 += ks2; x1 += k0 + 2u;
  TFR(13) TFR(15) TFR(26) TFR(6)   x0 += k0;  x1 += k1 + 3u;
  TFR(17) TFR(29) TFR(16) TFR(24)  x0 += k1;  x1 += ks2 + 4u;
  TFR(13) TFR(15) TFR(26) TFR(6)   x0 += ks2; x1 += k0 + 5u;
#undef TFR
  *o0 = x0; *o1 = x1;
}

__device__ static inline short f2bf(float f) {  // RNE fp32->bf16
  unsigned u = __float_as_uint(f);
  u = (u + 0x7fffu + ((u >> 16) & 1u)) >> 16;
  return (short)u;
}
__device__ static inline float bf2f(short s) {
  unsigned u = ((unsigned)(unsigned short)s) << 16;
  return __uint_as_float(u);
}
__device__ static inline float cvt_lo(unsigned d) {
  union { unsigned short u; _Float16 h; } c; c.u = (unsigned short)(d & 0xffffu);
  return (float)c.h;
}
__device__ static inline float cvt_hi(unsigned d) {
  union { unsigned short u; _Float16 h; } c; c.u = (unsigned short)(d >> 16);
  return (float)c.h;
}

__global__ void init_k(unsigned* flag) {
  if (threadIdx.x == 0) *flag = 0u;
}

// ---- prep: casts, transposes, tail copy, mask dtype detection ----
__global__ __launch_bounds__(256) void prep_k(
    const float* __restrict__ states, const unsigned* __restrict__ maskw,
    const float* __restrict__ Wf, const float* __restrict__ Uf,
    const float* __restrict__ bf_, const float* __restrict__ Wb,
    const float* __restrict__ Ub, const float* __restrict__ bb_,
    short* __restrict__ xb16, float* __restrict__ dout,
    short* __restrict__ Wt, short* __restrict__ Ut,
    float* __restrict__ biasc, float* __restrict__ brc,
    unsigned* __restrict__ flag) {
  const unsigned gid = blockIdx.x * 256 + threadIdx.x;  // 16,777,216 threads
  {  // states [b*512+t][512] -> xb16 t-major [t*64+b][512]
    unsigned c = gid & 511u, rw = gid >> 9;
    unsigned t = rw >> 6, b = rw & 63u;
    xb16[gid] = f2bf(states[(size_t)(b * 512 + t) * 512 + c]);
  }
  if (gid < 512000u) dout[16777216u + gid] = states[16777216u + gid];  // EXTRA tail
  if (gid < 2359296u) {  // W^T bf16: [l][n(1536)][k(512)]
    unsigned l = gid / 786432u, rem = gid % 786432u;
    unsigned n = rem >> 9, k = rem & 511u;
    float s = (n < 768u) ? Wf[(size_t)(l * 512 + k) * 768 + n]
                         : Wb[(size_t)(l * 512 + k) * 768 + (n - 768u)];
    Wt[gid] = f2bf(s);
  }
  if (gid < 1179648u) {  // U^T bf16: [(dir*3+l)][n(768)][k(256)]
    unsigned g = gid / 196608u, rem = gid % 196608u;
    unsigned dirv = g / 3u, l = g % 3u;
    unsigned n = rem >> 8, k = rem & 255u;
    const float* Usrc = dirv ? Ub : Uf;
    Ut[gid] = f2bf(Usrc[(size_t)(l * 256 + k) * 768 + n]);
  }
  if (gid < 4608u) {  // input bias concat [l][1536]; fold recur bias for z,r gates
    unsigned l = gid / 1536u, n = gid % 1536u;
    unsigned dirv = n / 768u, rem = n % 768u;
    const float* bsrc = dirv ? bb_ : bf_;
    float v = bsrc[(l * 2 + 0) * 768 + rem];
    if (rem < 512u) v += bsrc[(l * 2 + 1) * 768 + rem];   // z,r: additive -> fold
    biasc[gid] = v;
  }
  if (gid < 4608u) {  // recurrent bias [(dir*3+l)][768] (h-gate part used by gru)
    unsigned g = gid / 768u, n = gid % 768u;
    unsigned dirv = g / 3u, l = g % 3u;
    brc[gid] = (dirv ? bb_ : bf_)[(l * 2 + 1) * 768 + n];
  }
  if (gid < 8192u) {  // mask stored as bytes? any word >1 => yes
    if (maskw[gid] > 1u) atomicOr(flag, 1u);
  }
}

// ---- mask transpose: [b][t] (byte or word) -> bytes [t][64] ----
__global__ __launch_bounds__(256) void maskt_k(
    const unsigned char* __restrict__ mask8, const unsigned* __restrict__ flagp,
    unsigned char* __restrict__ maskt) {
  const unsigned gid = blockIdx.x * 256 + threadIdx.x;  // 32768
  const unsigned b = gid >> 9, t = gid & 511u;
  const bool mbyte = (*flagp) != 0u;
  unsigned v = mbyte ? (unsigned)mask8[gid] : ((const unsigned*)mask8)[gid];
  maskt[t * 64 + b] = v ? 1u : 0u;
}

// ---- projection GEMM: [32768,512]bf16 x [512,1536]bf16 -> fp16 + bias ----
// Output layout gru16-native, per (row,dir) block of 768 halves:
//   z,r packed:  [w(16)][col(16)][{z,r}]  at half-offset w*32 + col*2 + gate
//   h separate:  512 + w*16 + col
__global__ __launch_bounds__(256) void proj_gemm(
    const short* __restrict__ A, const short* __restrict__ Bt,
    const float* __restrict__ bias, _Float16* __restrict__ C) {
  __shared__ __align__(16) short As[4096];
  __shared__ __align__(16) short Bs[4096];
  const int tid = threadIdx.x;
  const int wave = tid >> 6, lane = tid & 63;
  const int col = lane & 15, kq = lane >> 4;
  const int wr = wave >> 1, wc = wave & 1;
  const int m0 = blockIdx.x * 128, n0 = blockIdx.y * 128;
  const uint4* Aq = (const uint4*)A;
  const uint4* Bq = (const uint4*)Bt;
  uint4* AsQ = (uint4*)As;
  uint4* BsQ = (uint4*)Bs;
  f32x4 acc[4][4];
#pragma unroll
  for (int i = 0; i < 4; ++i)
#pragma unroll
    for (int j = 0; j < 4; ++j) acc[i][j] = (f32x4){0.f, 0.f, 0.f, 0.f};

  for (int kt = 0; kt < 16; ++kt) {
    const int k8 = kt * 4;
#pragma unroll
    for (int rnd = 0; rnd < 2; ++rnd) {
      int chunk = rnd * 256 + tid;
      int row = chunk >> 2, kc = chunk & 3;
      AsQ[chunk] = Aq[(size_t)(m0 + row) * 64 + k8 + kc];
      BsQ[chunk] = Bq[(size_t)(n0 + row) * 64 + k8 + kc];
    }
    __syncthreads();
    short8 af[4], bfv[4];
#pragma unroll
    for (int i = 0; i < 4; ++i)
      af[i] = *(const short8*)(As + (wr * 64 + i * 16 + col) * 32 + kq * 8);
#pragma unroll
    for (int j = 0; j < 4; ++j)
      bfv[j] = *(const short8*)(Bs + (wc * 64 + j * 16 + col) * 32 + kq * 8);
#pragma unroll
    for (int i = 0; i < 4; ++i)
#pragma unroll
      for (int j = 0; j < 4; ++j)
        acc[i][j] = __builtin_amdgcn_mfma_f32_16x16x32_bf16(af[i], bfv[j], acc[i][j], 0, 0, 0);
    __syncthreads();
  }
#pragma unroll
  for (int j = 0; j < 4; ++j) {
    const int cg = n0 + wc * 64 + j * 16 + col;
    const float bv = bias[cg];
    const int dirv = cg / 768, rem = cg % 768;
    const int gate = rem >> 8, u = rem & 255;
    const int w = u >> 4, c = u & 15;
    const int colofs = dirv * 768 +
        ((gate < 2) ? (w * 32 + c * 2 + gate) : (512 + w * 16 + c));
#pragma unroll
    for (int i = 0; i < 4; ++i) {
      const int rb = m0 + wr * 64 + i * 16 + kq * 4;
#pragma unroll
      for (int r = 0; r < 4; ++r)
        C[(size_t)(rb + r) * 1536 + colofs] = (_Float16)(acc[i][j][r] + bv);
    }
  }
}

// ---- recurrent kernel: 8 blocks x 1024 threads (16 waves, 4 waves/SIMD) ----
// Wave w owns 16 units (one N-tile) for all 3 gates. z/r U^T frags in regs
// (64 VGPR); h-gate U^T staged in LDS [256][HB_STRIDE]. Per-thread: 24 MFMA,
// 16 ds_read_b128, 4 outputs per step. 4 waves/SIMD hides dependency stalls.
__global__ __launch_bounds__(1024, 4) void gru16(
    const _Float16* __restrict__ xp, const short* __restrict__ UtAll,
    const float* __restrict__ brcAll, const unsigned char* __restrict__ maskt,
    short* __restrict__ yout, int layer) {
  extern __shared__ short lds[];
  short* hgate = lds;                       // [256][HB_STRIDE] h-gate U^T
  short* hbuf  = lds + 256 * HB_STRIDE;     // [2][16][HB_STRIDE] h state (bf16)

  const int bid = blockIdx.x;
  const int dir = bid >> 2;
  const int b0 = (bid & 3) * 16;
  const int tid = threadIdx.x;
  const int wave = tid >> 6, lane = tid & 63;
  const int col = lane & 15, quad = lane >> 4;
  const int u = wave * 16 + col;            // owned unit
  const short* Ut = UtAll + (size_t)(dir * 3 + layer) * 768 * 256;
  const float* brc = brcAll + (dir * 3 + layer) * 768;

  // stage h-gate U^T rows [512,768) -> hgate, zero h buffers
  const short* Uth = Ut + 512 * 256;
  for (int c = tid; c < 8192; c += 1024) {
    int row = c >> 5, q = c & 31;
    *(uint4*)(hgate + row * HB_STRIDE + q * 8) = *(const uint4*)(Uth + row * 256 + q * 8);
  }
  for (int i = tid; i < 2 * HBLK; i += 1024) hbuf[i] = 0;

  // resident z/r U^T fragments: lane holds B[k=quad*8+j][n=u]
  short8 zB[8], rB[8];
#pragma unroll
  for (int ks = 0; ks < 8; ++ks) {
    zB[ks] = *(const short8*)(Ut + (size_t)u * 256 + ks * 32 + quad * 8);
    rB[ks] = *(const short8*)(Ut + (size_t)(256 + u) * 256 + ks * 32 + quad * 8);
  }
  const float brh = brc[512 + u];

  // xp addressing (bytes). row stride 3072 B; per-(row,dir) block 1536 B:
  //   zr dword at  dir*1536 + wave*64 + col*4
  //   h  ushort at dir*1536 + 1024 + wave*32 + col*2
  const int t0 = dir ? 511 : 0;
  const int tstep = dir ? -1 : 1;
  const int xstep = tstep * 64 * 3072;
  const char* xpb = (const char*)xp;
  const int row0 = (t0 * 64 + b0 + quad * 4);
  unsigned xzrA = (unsigned)(row0 * 3072 + dir * 1536 + wave * 64 + col * 4);
  unsigned xzrB = xzrA + 6144u;
  unsigned xhA  = (unsigned)(row0 * 3072 + dir * 1536 + 1024 + wave * 32 + col * 2);
  unsigned xhB  = xhA + 6144u;

  // LDS lane offsets
  const short* hgB = hgate + u * HB_STRIDE + quad * 8;
  const int rd_lane = col * HB_STRIDE + quad * 8;
  const int wr_lane = (quad * 4) * HB_STRIDE + u;

  // y addressing (bytes): row*1024 + dir*512 + u*2, row = t*64+b
  unsigned yoff = (unsigned)(row0 * 1024 + dir * 512 + u * 2);
  const int ystep = tstep * 65536;
  int moff = t0 * 64 + b0 + quad * 4;

  // prologue prefetch for s=0
  unsigned pzr[4], ph[4], pmc;
  pzr[0] = *(const unsigned*)(xpb + xzrA);
  pzr[1] = *(const unsigned*)(xpb + xzrA + 3072);
  pzr[2] = *(const unsigned*)(xpb + xzrB);
  pzr[3] = *(const unsigned*)(xpb + xzrB + 3072);
  ph[0] = *(const unsigned short*)(xpb + xhA);
  ph[1] = *(const unsigned short*)(xpb + xhA + 3072);
  ph[2] = *(const unsigned short*)(xpb + xhB);
  ph[3] = *(const unsigned short*)(xpb + xhB + 3072);
  pmc = *(const unsigned*)(maskt + moff);

  float hp[4] = {0.f, 0.f, 0.f, 0.f};
  __syncthreads();

  for (int s = 0; s < 512; ++s) {
    // init accumulators from prefetched projections (z,r) and recur bias (h)
    f32x4 az, ar, ah;
#pragma unroll
    for (int r = 0; r < 4; ++r) {
      az[r] = cvt_lo(pzr[r]);
      ar[r] = cvt_hi(pzr[r]);
      ah[r] = brh;
    }
    // issue next-step z/r prefetch (consumed at next init)
    if (s < 511) {
      xzrA += xstep; xzrB += xstep; xhA += xstep; xhB += xstep;
      pzr[0] = *(const unsigned*)(xpb + xzrA);
      pzr[1] = *(const unsigned*)(xpb + xzrA + 3072);
      pzr[2] = *(const unsigned*)(xpb + xzrB);
      pzr[3] = *(const unsigned*)(xpb + xzrB + 3072);
    }

    // recurrent matmul: h(t-1) @ U^T for z, r (reg frags) and h (LDS frags)
    const short* hrd = hbuf + (s & 1) * HBLK + rd_lane;
#pragma unroll
    for (int ks = 0; ks < 8; ++ks) {
      short8 a  = *(const short8*)(hrd + ks * 32);
      short8 hb = *(const short8*)(hgB + ks * 32);
      az = __builtin_amdgcn_mfma_f32_16x16x32_bf16(a, zB[ks], az, 0, 0, 0);
      ar = __builtin_amdgcn_mfma_f32_16x16x32_bf16(a, rB[ks], ar, 0, 0, 0);
      ah = __builtin_amdgcn_mfma_f32_16x16x32_bf16(a, hb,     ah, 0, 0, 0);
    }

    // epilogue: 4 outputs per thread
    short* hwr = hbuf + ((s & 1) ^ 1) * HBLK + wr_lane;
    char* yb = (char*)yout + yoff;
#pragma unroll
    for (int r = 0; r < 4; ++r) {
      float z  = 1.f / (1.f + __expf(-az[r]));
      float rr = 1.f / (1.f + __expf(-ar[r]));
      float xh = cvt_lo(ph[r]);
      float pre = xh + rr * ah[r];
      float hc = 1.f - 2.f / (__expf(2.f * pre) + 1.f);
      float hpv = hp[r];
      float hn = hc + z * (hpv - hc);
      hn = ((pmc >> (8 * r)) & 0xffu) ? hn : hpv;
      hp[r] = hn;
      short hnb = f2bf(hn);
      hwr[r * HB_STRIDE] = hnb;
      *(short*)(yb + r * 1024) = hnb;
    }
    yoff += ystep;
    // issue next-step h/mask prefetch (consumed at next epilogue)
    if (s < 511) {
      ph[0] = *(const unsigned short*)(xpb + xhA);
      ph[1] = *(const unsigned short*)(xpb + xhA + 3072);
      ph[2] = *(const unsigned short*)(xpb + xhB);
      ph[3] = *(const unsigned short*)(xpb + xhB + 3072);
      moff += tstep * 64;
      pmc = *(const unsigned*)(maskt + moff);
    }
    __syncthreads();
  }
}

// ---- dropout (JAX threefry partitionable); j == gid (t-major) ----
__global__ __launch_bounds__(256) void drop_k(
    short* __restrict__ xb16, float* __restrict__ dout,
    const int* __restrict__ training, unsigned k0, unsigned k1, int last) {
  const unsigned gid = blockIdx.x * 256 + threadIdx.x;
  float v = bf2f(xb16[gid]);
  unsigned y0, y1;
  tf2x32(k0, k1, 0u, gid, &y0, &y1);
  unsigned bits = y0 ^ y1;
  float u = __uint_as_float((bits >> 9) | 0x3f800000u) - 1.0f;
  bool keep = u < 0.9f;
  int tr = *training;
  float ov = tr ? (keep ? v * (1.0f / 0.9f) : 0.0f) : v;
  if (last) {
    unsigned r = gid >> 9, c = gid & 511u;
    unsigned t = r >> 6, b = r & 63u;
    dout[(size_t)(b * 512 + t) * 512 + c] = ov;
  } else {
    xb16[gid] = f2bf(ov);
  }
}

extern "C" void kernel_launch(void* const* d_in, const int* in_sizes, int n_in,
                              void* d_out, int out_size, void* d_ws, size_t ws_size,
                              hipStream_t stream) {
  (void)in_sizes; (void)n_in; (void)out_size; (void)ws_size;
  const float* states = (const float*)d_in[0];
  const void*  mask   = d_in[1];
  const int*   training = (const int*)d_in[3];
  const float* Wf = (const float*)d_in[4];
  const float* Uf = (const float*)d_in[5];
  const float* bf_ = (const float*)d_in[6];
  const float* Wb = (const float*)d_in[7];
  const float* Ub = (const float*)d_in[8];
  const float* bb_ = (const float*)d_in[9];
  char* ws = (char*)d_ws;

  short* xb16   = (short*)(ws + XB16_OFF);
  _Float16* xp  = (_Float16*)(ws + XP_OFF);
  short* Wt     = (short*)(ws + WT_OFF);
  short* Ut     = (short*)(ws + UT_OFF);
  float* biasc  = (float*)(ws + BIASC_OFF);
  float* brc    = (float*)(ws + BRC_OFF);
  unsigned char* maskt = (unsigned char*)(ws + MASKT_OFF);
  unsigned* flag = (unsigned*)(ws + FLAG_OFF);
  float* dout = (float*)d_out;

  // allow >64KB dynamic LDS for gru16 (idempotent; not a stream op)
  hipFuncSetAttribute((const void*)gru16,
                      hipFuncAttributeMaxDynamicSharedMemorySize, (int)LDS_BYTES);

  // threefry key chain: key(1234); per layer: dkey,sk = split(dkey)
  unsigned d0 = 0u, d1 = 1234u, sk0[3], sk1[3];
  for (int l = 0; l < 3; ++l) {
    unsigned a, b, c, d;
    tf2x32(d0, d1, 0u, 0u, &a, &b);   // new dkey
    tf2x32(d0, d1, 0u, 1u, &c, &d);   // subkey
    sk0[l] = c; sk1[l] = d;
    d0 = a; d1 = b;
  }

  init_k<<<1, 64, 0, stream>>>(flag);
  prep_k<<<65536, 256, 0, stream>>>(states, (const unsigned*)mask, Wf, Uf, bf_,
                                    Wb, Ub, bb_, xb16, dout, Wt, Ut, biasc, brc, flag);
  maskt_k<<<128, 256, 0, stream>>>((const unsigned char*)mask, flag, maskt);
  for (int l = 0; l < 3; ++l) {
    proj_gemm<<<dim3(256, 12), 256, 0, stream>>>(xb16, Wt + (size_t)l * 1536 * 512,
                                                 biasc + l * 1536, xp);
    gru16<<<8, 1024, LDS_BYTES, stream>>>(xp, Ut, brc, maskt, xb16, l);
    drop_k<<<65536, 256, 0, stream>>>(xb16, dout, training, sk0[l], sk1[l], l == 2);
  }
}

// Round 3
// 4129.107 us; speedup vs baseline: 1.2674x; 1.0172x over previous
//
#include <hip/hip_runtime.h>
#include <stdint.h>

typedef __attribute__((ext_vector_type(8))) short short8;
typedef __attribute__((ext_vector_type(4))) float f32x4;

// ---- workspace byte offsets (total ~141.8 MB) ----
#define XB16_OFF  0UL           // bf16 layer input/output [t*64+b][512]   32 MB
#define XP_OFF    33554432UL    // fp16 projections, gru-native layout     96 MB
#define WT_OFF    134217728UL   // bf16 W^T  [3][1536][512]               4.5 MB
#define UT_OFF    138936320UL   // bf16 U^T  [dir*3+l][768][256]         2.25 MB
#define BIASC_OFF 141295616UL   // fp32 input bias (+recur bias for z,r) [3][1536]
#define BRC_OFF   141314048UL   // fp32 recur bias [dir*3+l][768]
#define MASKT_OFF 141332480UL   // byte mask transposed [t][64]           32 KB
#define FLAG_OFF  141725760UL   // mask-dtype flag

#define HB_STRIDE 264           // 256 + 8 pad halves (conflict-free b128 reads)
#define HBLK (16 * HB_STRIDE)
// LDS: h-gate U^T [256][HB_STRIDE] + h state double buffer [2][16][HB_STRIDE]
#define LDS_BYTES (((size_t)256 * HB_STRIDE + 2 * HBLK) * 2)

// LDS-only barrier: h double-buffer hazards are all lgkmcnt-counted (ds reads
// land in VGPRs, ds writes commit to LDS). Avoids __syncthreads' vmcnt(0)
// drain, which would stall every step on in-flight xp prefetches / y stores.
#define LDS_BARRIER() asm volatile("s_waitcnt lgkmcnt(0)\n\ts_barrier" ::: "memory")

// ---- threefry2x32, 20 rounds (jax partitionable mode) ----
__host__ __device__ static inline void tf2x32(unsigned k0, unsigned k1,
                                              unsigned x0, unsigned x1,
                                              unsigned* o0, unsigned* o1) {
  unsigned ks2 = k0 ^ k1 ^ 0x1BD11BDAu;
#define TFR(r) { x0 += x1; x1 = (x1 << (r)) | (x1 >> (32 - (r))); x1 ^= x0; }
  x0 += k0; x1 += k1;
  TFR(13) TFR(15) TFR(26) TFR(6)   x0 += k1;  x1 += ks2 + 1u;
  TFR(17) TFR(29) TFR(16) TFR(24)  x0 += ks2; x1 += k0 + 2u;
  TFR(13) TFR(15) TFR(26) TFR(6)   x0 += k0;  x1 += k1 + 3u;
  TFR(17) TFR(29) TFR(16) TFR(24)  x0 += k1;  x1 += ks2 + 4u;
  TFR(13) TFR(15) TFR(26) TFR(6)   x0 += ks2; x1 += k0 + 5u;
#undef TFR
  *o0 = x0; *o1 = x1;
}

__device__ static inline short f2bf(float f) {  // RNE fp32->bf16
  unsigned u = __float_as_uint(f);
  u = (u + 0x7fffu + ((u >> 16) & 1u)) >> 16;
  return (short)u;
}
__device__ static inline float bf2f(short s) {
  unsigned u = ((unsigned)(unsigned short)s) << 16;
  return __uint_as_float(u);
}
__device__ static inline float cvt_lo(unsigned d) {
  union { unsigned short u; _Float16 h; } c; c.u = (unsigned short)(d & 0xffffu);
  return (float)c.h;
}
__device__ static inline float cvt_hi(unsigned d) {
  union { unsigned short u; _Float16 h; } c; c.u = (unsigned short)(d >> 16);
  return (float)c.h;
}

__global__ void init_k(unsigned* flag) {
  if (threadIdx.x == 0) *flag = 0u;
}

// ---- prep: casts, transposes, tail copy, mask dtype detection ----
__global__ __launch_bounds__(256) void prep_k(
    const float* __restrict__ states, const unsigned* __restrict__ maskw,
    const float* __restrict__ Wf, const float* __restrict__ Uf,
    const float* __restrict__ bf_, const float* __restrict__ Wb,
    const float* __restrict__ Ub, const float* __restrict__ bb_,
    short* __restrict__ xb16, float* __restrict__ dout,
    short* __restrict__ Wt, short* __restrict__ Ut,
    float* __restrict__ biasc, float* __restrict__ brc,
    unsigned* __restrict__ flag) {
  const unsigned gid = blockIdx.x * 256 + threadIdx.x;  // 16,777,216 threads
  {  // states [b*512+t][512] -> xb16 t-major [t*64+b][512]
    unsigned c = gid & 511u, rw = gid >> 9;
    unsigned t = rw >> 6, b = rw & 63u;
    xb16[gid] = f2bf(states[(size_t)(b * 512 + t) * 512 + c]);
  }
  if (gid < 512000u) dout[16777216u + gid] = states[16777216u + gid];  // EXTRA tail
  if (gid < 2359296u) {  // W^T bf16: [l][n(1536)][k(512)]
    unsigned l = gid / 786432u, rem = gid % 786432u;
    unsigned n = rem >> 9, k = rem & 511u;
    float s = (n < 768u) ? Wf[(size_t)(l * 512 + k) * 768 + n]
                         : Wb[(size_t)(l * 512 + k) * 768 + (n - 768u)];
    Wt[gid] = f2bf(s);
  }
  if (gid < 1179648u) {  // U^T bf16: [(dir*3+l)][n(768)][k(256)]
    unsigned g = gid / 196608u, rem = gid % 196608u;
    unsigned dirv = g / 3u, l = g % 3u;
    unsigned n = rem >> 8, k = rem & 255u;
    const float* Usrc = dirv ? Ub : Uf;
    Ut[gid] = f2bf(Usrc[(size_t)(l * 256 + k) * 768 + n]);
  }
  if (gid < 4608u) {  // input bias concat [l][1536]; fold recur bias for z,r gates
    unsigned l = gid / 1536u, n = gid % 1536u;
    unsigned dirv = n / 768u, rem = n % 768u;
    const float* bsrc = dirv ? bb_ : bf_;
    float v = bsrc[(l * 2 + 0) * 768 + rem];
    if (rem < 512u) v += bsrc[(l * 2 + 1) * 768 + rem];   // z,r: additive -> fold
    biasc[gid] = v;
  }
  if (gid < 4608u) {  // recurrent bias [(dir*3+l)][768] (h-gate part used by gru)
    unsigned g = gid / 768u, n = gid % 768u;
    unsigned dirv = g / 3u, l = g % 3u;
    brc[gid] = (dirv ? bb_ : bf_)[(l * 2 + 1) * 768 + n];
  }
  if (gid < 8192u) {  // mask stored as bytes? any word >1 => yes
    if (maskw[gid] > 1u) atomicOr(flag, 1u);
  }
}

// ---- mask transpose: [b][t] (byte or word) -> bytes [t][64] ----
__global__ __launch_bounds__(256) void maskt_k(
    const unsigned char* __restrict__ mask8, const unsigned* __restrict__ flagp,
    unsigned char* __restrict__ maskt) {
  const unsigned gid = blockIdx.x * 256 + threadIdx.x;  // 32768
  const unsigned b = gid >> 9, t = gid & 511u;
  const bool mbyte = (*flagp) != 0u;
  unsigned v = mbyte ? (unsigned)mask8[gid] : ((const unsigned*)mask8)[gid];
  maskt[t * 64 + b] = v ? 1u : 0u;
}

// ---- projection GEMM: [32768,512]bf16 x [512,1536]bf16 -> fp16 + bias ----
// Output layout gru16-native, per (row,dir) block of 768 halves:
//   z,r packed:  [w(16)][col(16)][{z,r}]  at half-offset w*32 + col*2 + gate
//   h separate:  512 + w*16 + col
__global__ __launch_bounds__(256) void proj_gemm(
    const short* __restrict__ A, const short* __restrict__ Bt,
    const float* __restrict__ bias, _Float16* __restrict__ C) {
  __shared__ __align__(16) short As[4096];
  __shared__ __align__(16) short Bs[4096];
  const int tid = threadIdx.x;
  const int wave = tid >> 6, lane = tid & 63;
  const int col = lane & 15, kq = lane >> 4;
  const int wr = wave >> 1, wc = wave & 1;
  const int m0 = blockIdx.x * 128, n0 = blockIdx.y * 128;
  const uint4* Aq = (const uint4*)A;
  const uint4* Bq = (const uint4*)Bt;
  uint4* AsQ = (uint4*)As;
  uint4* BsQ = (uint4*)Bs;
  f32x4 acc[4][4];
#pragma unroll
  for (int i = 0; i < 4; ++i)
#pragma unroll
    for (int j = 0; j < 4; ++j) acc[i][j] = (f32x4){0.f, 0.f, 0.f, 0.f};

  for (int kt = 0; kt < 16; ++kt) {
    const int k8 = kt * 4;
#pragma unroll
    for (int rnd = 0; rnd < 2; ++rnd) {
      int chunk = rnd * 256 + tid;
      int row = chunk >> 2, kc = chunk & 3;
      AsQ[chunk] = Aq[(size_t)(m0 + row) * 64 + k8 + kc];
      BsQ[chunk] = Bq[(size_t)(n0 + row) * 64 + k8 + kc];
    }
    __syncthreads();
    short8 af[4], bfv[4];
#pragma unroll
    for (int i = 0; i < 4; ++i)
      af[i] = *(const short8*)(As + (wr * 64 + i * 16 + col) * 32 + kq * 8);
#pragma unroll
    for (int j = 0; j < 4; ++j)
      bfv[j] = *(const short8*)(Bs + (wc * 64 + j * 16 + col) * 32 + kq * 8);
#pragma unroll
    for (int i = 0; i < 4; ++i)
#pragma unroll
      for (int j = 0; j < 4; ++j)
        acc[i][j] = __builtin_amdgcn_mfma_f32_16x16x32_bf16(af[i], bfv[j], acc[i][j], 0, 0, 0);
    __syncthreads();
  }
#pragma unroll
  for (int j = 0; j < 4; ++j) {
    const int cg = n0 + wc * 64 + j * 16 + col;
    const float bv = bias[cg];
    const int dirv = cg / 768, rem = cg % 768;
    const int gate = rem >> 8, u = rem & 255;
    const int w = u >> 4, c = u & 15;
    const int colofs = dirv * 768 +
        ((gate < 2) ? (w * 32 + c * 2 + gate) : (512 + w * 16 + c));
#pragma unroll
    for (int i = 0; i < 4; ++i) {
      const int rb = m0 + wr * 64 + i * 16 + kq * 4;
#pragma unroll
      for (int r = 0; r < 4; ++r)
        C[(size_t)(rb + r) * 1536 + colofs] = (_Float16)(acc[i][j][r] + bv);
    }
  }
}

// ---- recurrent kernel: 8 blocks x 1024 threads (16 waves, 4 waves/SIMD) ----
// Wave w owns 16 units (one N-tile) for all 3 gates. z/r U^T frags in regs
// (64 VGPR); h-gate U^T staged in LDS [256][HB_STRIDE]. Per-thread: 24 MFMA,
// 16 ds_read_b128, 4 outputs per step. Per-step barrier is LDS-only so
// global xp prefetches / y stores stay in flight across steps.
__global__ __launch_bounds__(1024, 4) void gru16(
    const _Float16* __restrict__ xp, const short* __restrict__ UtAll,
    const float* __restrict__ brcAll, const unsigned char* __restrict__ maskt,
    short* __restrict__ yout, int layer) {
  extern __shared__ short lds[];
  short* hgate = lds;                       // [256][HB_STRIDE] h-gate U^T
  short* hbuf  = lds + 256 * HB_STRIDE;     // [2][16][HB_STRIDE] h state (bf16)

  const int bid = blockIdx.x;
  const int dir = bid >> 2;
  const int b0 = (bid & 3) * 16;
  const int tid = threadIdx.x;
  const int wave = tid >> 6, lane = tid & 63;
  const int col = lane & 15, quad = lane >> 4;
  const int u = wave * 16 + col;            // owned unit
  const short* Ut = UtAll + (size_t)(dir * 3 + layer) * 768 * 256;
  const float* brc = brcAll + (dir * 3 + layer) * 768;

  // stage h-gate U^T rows [512,768) -> hgate, zero h buffers
  const short* Uth = Ut + 512 * 256;
  for (int c = tid; c < 8192; c += 1024) {
    int row = c >> 5, q = c & 31;
    *(uint4*)(hgate + row * HB_STRIDE + q * 8) = *(const uint4*)(Uth + row * 256 + q * 8);
  }
  for (int i = tid; i < 2 * HBLK; i += 1024) hbuf[i] = 0;

  // resident z/r U^T fragments: lane holds B[k=quad*8+j][n=u]
  short8 zB[8], rB[8];
#pragma unroll
  for (int ks = 0; ks < 8; ++ks) {
    zB[ks] = *(const short8*)(Ut + (size_t)u * 256 + ks * 32 + quad * 8);
    rB[ks] = *(const short8*)(Ut + (size_t)(256 + u) * 256 + ks * 32 + quad * 8);
  }
  const float brh = brc[512 + u];

  // xp addressing (bytes). row stride 3072 B; per-(row,dir) block 1536 B:
  //   zr dword at  dir*1536 + wave*64 + col*4
  //   h  ushort at dir*1536 + 1024 + wave*32 + col*2
  const int t0 = dir ? 511 : 0;
  const int tstep = dir ? -1 : 1;
  const int xstep = tstep * 64 * 3072;
  const char* xpb = (const char*)xp;
  const int row0 = (t0 * 64 + b0 + quad * 4);
  unsigned xzrA = (unsigned)(row0 * 3072 + dir * 1536 + wave * 64 + col * 4);
  unsigned xzrB = xzrA + 6144u;
  unsigned xhA  = (unsigned)(row0 * 3072 + dir * 1536 + 1024 + wave * 32 + col * 2);
  unsigned xhB  = xhA + 6144u;

  // LDS lane offsets
  const short* hgB = hgate + u * HB_STRIDE + quad * 8;
  const int rd_lane = col * HB_STRIDE + quad * 8;
  const int wr_lane = (quad * 4) * HB_STRIDE + u;

  // y addressing (bytes): row*1024 + dir*512 + u*2, row = t*64+b
  unsigned yoff = (unsigned)(row0 * 1024 + dir * 512 + u * 2);
  const int ystep = tstep * 65536;
  int moff = t0 * 64 + b0 + quad * 4;

  // prologue prefetch for s=0
  unsigned pzr[4], ph[4], pmc;
  pzr[0] = *(const unsigned*)(xpb + xzrA);
  pzr[1] = *(const unsigned*)(xpb + xzrA + 3072);
  pzr[2] = *(const unsigned*)(xpb + xzrB);
  pzr[3] = *(const unsigned*)(xpb + xzrB + 3072);
  ph[0] = *(const unsigned short*)(xpb + xhA);
  ph[1] = *(const unsigned short*)(xpb + xhA + 3072);
  ph[2] = *(const unsigned short*)(xpb + xhB);
  ph[3] = *(const unsigned short*)(xpb + xhB + 3072);
  pmc = *(const unsigned*)(maskt + moff);

  float hp[4] = {0.f, 0.f, 0.f, 0.f};
  __syncthreads();

  for (int s = 0; s < 512; ++s) {
    // init accumulators from prefetched projections (z,r) and recur bias (h)
    f32x4 az, ar, ah;
#pragma unroll
    for (int r = 0; r < 4; ++r) {
      az[r] = cvt_lo(pzr[r]);
      ar[r] = cvt_hi(pzr[r]);
      ah[r] = brh;
    }
    // issue next-step z/r prefetch (consumed at next init)
    if (s < 511) {
      xzrA += xstep; xzrB += xstep; xhA += xstep; xhB += xstep;
      pzr[0] = *(const unsigned*)(xpb + xzrA);
      pzr[1] = *(const unsigned*)(xpb + xzrA + 3072);
      pzr[2] = *(const unsigned*)(xpb + xzrB);
      pzr[3] = *(const unsigned*)(xpb + xzrB + 3072);
    }

    // recurrent matmul: h(t-1) @ U^T for z, r (reg frags) and h (LDS frags)
    const short* hrd = hbuf + (s & 1) * HBLK + rd_lane;
#pragma unroll
    for (int ks = 0; ks < 8; ++ks) {
      short8 a  = *(const short8*)(hrd + ks * 32);
      short8 hb = *(const short8*)(hgB + ks * 32);
      az = __builtin_amdgcn_mfma_f32_16x16x32_bf16(a, zB[ks], az, 0, 0, 0);
      ar = __builtin_amdgcn_mfma_f32_16x16x32_bf16(a, rB[ks], ar, 0, 0, 0);
      ah = __builtin_amdgcn_mfma_f32_16x16x32_bf16(a, hb,     ah, 0, 0, 0);
    }

    // epilogue: 4 outputs per thread
    short* hwr = hbuf + ((s & 1) ^ 1) * HBLK + wr_lane;
    char* yb = (char*)yout + yoff;
#pragma unroll
    for (int r = 0; r < 4; ++r) {
      float z  = 1.f / (1.f + __expf(-az[r]));
      float rr = 1.f / (1.f + __expf(-ar[r]));
      float xh = cvt_lo(ph[r]);
      float pre = xh + rr * ah[r];
      float hc = 1.f - 2.f / (__expf(2.f * pre) + 1.f);
      float hpv = hp[r];
      float hn = hc + z * (hpv - hc);
      hn = ((pmc >> (8 * r)) & 0xffu) ? hn : hpv;
      hp[r] = hn;
      short hnb = f2bf(hn);
      hwr[r * HB_STRIDE] = hnb;
      *(short*)(yb + r * 1024) = hnb;
    }
    yoff += ystep;
    // issue next-step h/mask prefetch (consumed at next epilogue)
    if (s < 511) {
      ph[0] = *(const unsigned short*)(xpb + xhA);
      ph[1] = *(const unsigned short*)(xpb + xhA + 3072);
      ph[2] = *(const unsigned short*)(xpb + xhB);
      ph[3] = *(const unsigned short*)(xpb + xhB + 3072);
      moff += tstep * 64;
      pmc = *(const unsigned*)(maskt + moff);
    }
    // LDS-only barrier (no vmcnt drain): global ops stay in flight
    LDS_BARRIER();
  }
}

// ---- dropout (JAX threefry partitionable); j == gid (t-major) ----
__global__ __launch_bounds__(256) void drop_k(
    short* __restrict__ xb16, float* __restrict__ dout,
    const int* __restrict__ training, unsigned k0, unsigned k1, int last) {
  const unsigned gid = blockIdx.x * 256 + threadIdx.x;
  float v = bf2f(xb16[gid]);
  unsigned y0, y1;
  tf2x32(k0, k1, 0u, gid, &y0, &y1);
  unsigned bits = y0 ^ y1;
  float u = __uint_as_float((bits >> 9) | 0x3f800000u) - 1.0f;
  bool keep = u < 0.9f;
  int tr = *training;
  float ov = tr ? (keep ? v * (1.0f / 0.9f) : 0.0f) : v;
  if (last) {
    unsigned r = gid >> 9, c = gid & 511u;
    unsigned t = r >> 6, b = r & 63u;
    dout[(size_t)(b * 512 + t) * 512 + c] = ov;
  } else {
    xb16[gid] = f2bf(ov);
  }
}

extern "C" void kernel_launch(void* const* d_in, const int* in_sizes, int n_in,
                              void* d_out, int out_size, void* d_ws, size_t ws_size,
                              hipStream_t stream) {
  (void)in_sizes; (void)n_in; (void)out_size; (void)ws_size;
  const float* states = (const float*)d_in[0];
  const void*  mask   = d_in[1];
  const int*   training = (const int*)d_in[3];
  const float* Wf = (const float*)d_in[4];
  const float* Uf = (const float*)d_in[5];
  const float* bf_ = (const float*)d_in[6];
  const float* Wb = (const float*)d_in[7];
  const float* Ub = (const float*)d_in[8];
  const float* bb_ = (const float*)d_in[9];
  char* ws = (char*)d_ws;

  short* xb16   = (short*)(ws + XB16_OFF);
  _Float16* xp  = (_Float16*)(ws + XP_OFF);
  short* Wt     = (short*)(ws + WT_OFF);
  short* Ut     = (short*)(ws + UT_OFF);
  float* biasc  = (float*)(ws + BIASC_OFF);
  float* brc    = (float*)(ws + BRC_OFF);
  unsigned char* maskt = (unsigned char*)(ws + MASKT_OFF);
  unsigned* flag = (unsigned*)(ws + FLAG_OFF);
  float* dout = (float*)d_out;

  // allow >64KB dynamic LDS for gru16 (idempotent; not a stream op)
  hipFuncSetAttribute((const void*)gru16,
                      hipFuncAttributeMaxDynamicSharedMemorySize, (int)LDS_BYTES);

  // threefry key chain: key(1234); per layer: dkey,sk = split(dkey)
  unsigned d0 = 0u, d1 = 1234u, sk0[3], sk1[3];
  for (int l = 0; l < 3; ++l) {
    unsigned a, b, c, d;
    tf2x32(d0, d1, 0u, 0u, &a, &b);   // new dkey
    tf2x32(d0, d1, 0u, 1u, &c, &d);   // subkey
    sk0[l] = c; sk1[l] = d;
    d0 = a; d1 = b;
  }

  init_k<<<1, 64, 0, stream>>>(flag);
  prep_k<<<65536, 256, 0, stream>>>(states, (const unsigned*)mask, Wf, Uf, bf_,
                                    Wb, Ub, bb_, xb16, dout, Wt, Ut, biasc, brc, flag);
  maskt_k<<<128, 256, 0, stream>>>((const unsigned char*)mask, flag, maskt);
  for (int l = 0; l < 3; ++l) {
    proj_gemm<<<dim3(256, 12), 256, 0, stream>>>(xb16, Wt + (size_t)l * 1536 * 512,
                                                 biasc + l * 1536, xp);
    gru16<<<8, 1024, LDS_BYTES, stream>>>(xp, Ut, brc, maskt, xb16, l);
    drop_k<<<65536, 256, 0, stream>>>(xb16, dout, training, sk0[l], sk1[l], l == 2);
  }
}

// Round 4
// 3797.279 us; speedup vs baseline: 1.3781x; 1.0874x over previous
//
#include <hip/hip_runtime.h>
#include <stdint.h>

typedef __attribute__((ext_vector_type(8))) short short8;
typedef __attribute__((ext_vector_type(4))) float f32x4;

// ---- workspace byte offsets (total ~141.8 MB) ----
#define XB16_OFF  0UL           // bf16 layer input/output [t*64+b][512]   32 MB
#define XP_OFF    33554432UL    // fp16 projections [t][dir][b][gate][u]   96 MB
#define WT_OFF    134217728UL   // bf16 W^T  [3][1536][512]               4.5 MB
#define UT_OFF    138936320UL   // bf16 U^T  [dir*3+l][768][256]         2.25 MB
#define BIASC_OFF 141295616UL   // fp32 input bias (+recur bias for z,r) [3][1536]
#define BRC_OFF   141314048UL   // fp32 recur bias [dir*3+l][768]
#define MASKT_OFF 141332480UL   // byte mask transposed [t][64]           32 KB
#define FLAG_OFF  141725760UL   // mask-dtype flag

#define HB_STRIDE 264           // 256 + 8 pad halves (conflict-free b128 reads)
#define HBLK (16 * HB_STRIDE)
// LDS: h-gate U^T [256][HB_STRIDE] + h state double buffer [2][16][HB_STRIDE]
#define LDS_BYTES (((size_t)256 * HB_STRIDE + 2 * HBLK) * 2)

// LDS-only barrier: h double-buffer hazards are all lgkmcnt-counted. Avoids
// __syncthreads' vmcnt(0) drain so global loads/stores ride across steps.
#define LDS_BARRIER() asm volatile("s_waitcnt lgkmcnt(0)\n\ts_barrier" ::: "memory")

// ---- threefry2x32, 20 rounds (jax partitionable mode) ----
__host__ __device__ static inline void tf2x32(unsigned k0, unsigned k1,
                                              unsigned x0, unsigned x1,
                                              unsigned* o0, unsigned* o1) {
  unsigned ks2 = k0 ^ k1 ^ 0x1BD11BDAu;
#define TFR(r) { x0 += x1; x1 = (x1 << (r)) | (x1 >> (32 - (r))); x1 ^= x0; }
  x0 += k0; x1 += k1;
  TFR(13) TFR(15) TFR(26) TFR(6)   x0 += k1;  x1 += ks2 + 1u;
  TFR(17) TFR(29) TFR(16) TFR(24)  x0 += ks2; x1 += k0 + 2u;
  TFR(13) TFR(15) TFR(26) TFR(6)   x0 += k0;  x1 += k1 + 3u;
  TFR(17) TFR(29) TFR(16) TFR(24)  x0 += k1;  x1 += ks2 + 4u;
  TFR(13) TFR(15) TFR(26) TFR(6)   x0 += ks2; x1 += k0 + 5u;
#undef TFR
  *o0 = x0; *o1 = x1;
}

__device__ static inline short f2bf(float f) {  // RNE fp32->bf16
  unsigned u = __float_as_uint(f);
  u = (u + 0x7fffu + ((u >> 16) & 1u)) >> 16;
  return (short)u;
}
__device__ static inline float bf2f(short s) {
  unsigned u = ((unsigned)(unsigned short)s) << 16;
  return __uint_as_float(u);
}
__device__ static inline float cvt_lo(unsigned d) {
  union { unsigned short u; _Float16 h; } c; c.u = (unsigned short)(d & 0xffffu);
  return (float)c.h;
}
__device__ static inline float cvt_hi(unsigned d) {
  union { unsigned short u; _Float16 h; } c; c.u = (unsigned short)(d >> 16);
  return (float)c.h;
}

__global__ void init_k(unsigned* flag) {
  if (threadIdx.x == 0) *flag = 0u;
}

// ---- prep: casts, transposes, tail copy, mask dtype detection ----
__global__ __launch_bounds__(256) void prep_k(
    const float* __restrict__ states, const unsigned* __restrict__ maskw,
    const float* __restrict__ Wf, const float* __restrict__ Uf,
    const float* __restrict__ bf_, const float* __restrict__ Wb,
    const float* __restrict__ Ub, const float* __restrict__ bb_,
    short* __restrict__ xb16, float* __restrict__ dout,
    short* __restrict__ Wt, short* __restrict__ Ut,
    float* __restrict__ biasc, float* __restrict__ brc,
    unsigned* __restrict__ flag) {
  const unsigned gid = blockIdx.x * 256 + threadIdx.x;  // 16,777,216 threads
  {  // states [b*512+t][512] -> xb16 t-major [t*64+b][512]
    unsigned c = gid & 511u, rw = gid >> 9;
    unsigned t = rw >> 6, b = rw & 63u;
    xb16[gid] = f2bf(states[(size_t)(b * 512 + t) * 512 + c]);
  }
  if (gid < 512000u) dout[16777216u + gid] = states[16777216u + gid];  // EXTRA tail
  if (gid < 2359296u) {  // W^T bf16: [l][n(1536)][k(512)]
    unsigned l = gid / 786432u, rem = gid % 786432u;
    unsigned n = rem >> 9, k = rem & 511u;
    float s = (n < 768u) ? Wf[(size_t)(l * 512 + k) * 768 + n]
                         : Wb[(size_t)(l * 512 + k) * 768 + (n - 768u)];
    Wt[gid] = f2bf(s);
  }
  if (gid < 1179648u) {  // U^T bf16: [(dir*3+l)][n(768)][k(256)]
    unsigned g = gid / 196608u, rem = gid % 196608u;
    unsigned dirv = g / 3u, l = g % 3u;
    unsigned n = rem >> 8, k = rem & 255u;
    const float* Usrc = dirv ? Ub : Uf;
    Ut[gid] = f2bf(Usrc[(size_t)(l * 256 + k) * 768 + n]);
  }
  if (gid < 4608u) {  // input bias concat [l][1536]; fold recur bias for z,r gates
    unsigned l = gid / 1536u, n = gid % 1536u;
    unsigned dirv = n / 768u, rem = n % 768u;
    const float* bsrc = dirv ? bb_ : bf_;
    float v = bsrc[(l * 2 + 0) * 768 + rem];
    if (rem < 512u) v += bsrc[(l * 2 + 1) * 768 + rem];   // z,r: additive -> fold
    biasc[gid] = v;
  }
  if (gid < 4608u) {  // recurrent bias [(dir*3+l)][768] (h-gate part used by gru)
    unsigned g = gid / 768u, n = gid % 768u;
    unsigned dirv = g / 3u, l = g % 3u;
    brc[gid] = (dirv ? bb_ : bf_)[(l * 2 + 1) * 768 + n];
  }
  if (gid < 8192u) {  // mask stored as bytes? any word >1 => yes
    if (maskw[gid] > 1u) atomicOr(flag, 1u);
  }
}

// ---- mask transpose: [b][t] (byte or word) -> bytes [t][64] ----
__global__ __launch_bounds__(256) void maskt_k(
    const unsigned char* __restrict__ mask8, const unsigned* __restrict__ flagp,
    unsigned char* __restrict__ maskt) {
  const unsigned gid = blockIdx.x * 256 + threadIdx.x;  // 32768
  const unsigned b = gid >> 9, t = gid & 511u;
  const bool mbyte = (*flagp) != 0u;
  unsigned v = mbyte ? (unsigned)mask8[gid] : ((const unsigned*)mask8)[gid];
  maskt[t * 64 + b] = v ? 1u : 0u;
}

// ---- projection GEMM: [32768,512]bf16 x [512,1536]bf16 -> fp16 + bias ----
// Output layout: xp[t][dir][b][gate][u] fp16 (768 halves per (t,dir,b)):
//   half index = ((t*2+dir)*64 + b)*768 + gate*256 + u
__global__ __launch_bounds__(256) void proj_gemm(
    const short* __restrict__ A, const short* __restrict__ Bt,
    const float* __restrict__ bias, _Float16* __restrict__ C) {
  __shared__ __align__(16) short As[4096];
  __shared__ __align__(16) short Bs[4096];
  const int tid = threadIdx.x;
  const int wave = tid >> 6, lane = tid & 63;
  const int col = lane & 15, kq = lane >> 4;
  const int wr = wave >> 1, wc = wave & 1;
  const int m0 = blockIdx.x * 128, n0 = blockIdx.y * 128;
  const uint4* Aq = (const uint4*)A;
  const uint4* Bq = (const uint4*)Bt;
  uint4* AsQ = (uint4*)As;
  uint4* BsQ = (uint4*)Bs;
  f32x4 acc[4][4];
#pragma unroll
  for (int i = 0; i < 4; ++i)
#pragma unroll
    for (int j = 0; j < 4; ++j) acc[i][j] = (f32x4){0.f, 0.f, 0.f, 0.f};

  for (int kt = 0; kt < 16; ++kt) {
    const int k8 = kt * 4;
#pragma unroll
    for (int rnd = 0; rnd < 2; ++rnd) {
      int chunk = rnd * 256 + tid;
      int row = chunk >> 2, kc = chunk & 3;
      AsQ[chunk] = Aq[(size_t)(m0 + row) * 64 + k8 + kc];
      BsQ[chunk] = Bq[(size_t)(n0 + row) * 64 + k8 + kc];
    }
    __syncthreads();
    short8 af[4], bfv[4];
#pragma unroll
    for (int i = 0; i < 4; ++i)
      af[i] = *(const short8*)(As + (wr * 64 + i * 16 + col) * 32 + kq * 8);
#pragma unroll
    for (int j = 0; j < 4; ++j)
      bfv[j] = *(const short8*)(Bs + (wc * 64 + j * 16 + col) * 32 + kq * 8);
#pragma unroll
    for (int i = 0; i < 4; ++i)
#pragma unroll
      for (int j = 0; j < 4; ++j)
        acc[i][j] = __builtin_amdgcn_mfma_f32_16x16x32_bf16(af[i], bfv[j], acc[i][j], 0, 0, 0);
    __syncthreads();
  }
  // m = m0 + wr*64 + (i*16+kq*4+r): t = m>>6 = (m0>>6)+wr (const), b = i*16+kq*4+r
#pragma unroll
  for (int j = 0; j < 4; ++j) {
    const int cg = n0 + wc * 64 + j * 16 + col;
    const float bv = bias[cg];
    const int dirv = cg / 768, rem = cg % 768;
    const int gate = rem >> 8, u = rem & 255;
    const size_t cbase =
        ((size_t)(((m0 >> 6) + wr) * 2 + dirv)) * 49152 + gate * 256 + u;
#pragma unroll
    for (int i = 0; i < 4; ++i) {
#pragma unroll
      for (int r = 0; r < 4; ++r)
        C[cbase + (size_t)(i * 16 + kq * 4 + r) * 768] = (_Float16)(acc[i][j][r] + bv);
    }
  }
}

// ---- recurrent kernel: 8 blocks x 1024 threads (16 waves, 4 waves/SIMD) ----
// TRANSPOSED mapping: D[m=unit][n=batch]. Wave w owns units [w*16,w*16+16);
// A = U^T (static: z/r frags in regs, h-gate staged in LDS), B = h(t-1) from
// LDS. Thread (col,quad) produces units w*16+quad*4..+3 for batch row col ->
// all per-thread I/O is contiguous: 3 b64 xp loads (one base + imm offsets),
// 1 b64 ds_write, 1 b64 y store, 1 mask byte, 2 v_cvt_pk_bf16_f32 packs.
__global__ __launch_bounds__(1024, 4) void gru16(
    const _Float16* __restrict__ xp, const short* __restrict__ UtAll,
    const float* __restrict__ brcAll, const unsigned char* __restrict__ maskt,
    short* __restrict__ yout, int layer) {
  extern __shared__ short lds[];
  short* hgate = lds;                       // [256][HB_STRIDE] h-gate U^T
  short* hbuf  = lds + 256 * HB_STRIDE;     // [2][16][HB_STRIDE] h state (bf16)

  const int bid = blockIdx.x;
  const int dir = bid >> 2;
  const int b0 = (bid & 3) * 16;
  const int tid = threadIdx.x;
  const int wave = tid >> 6, lane = tid & 63;
  const int col = lane & 15, quad = lane >> 4;
  const int u0 = wave * 16 + quad * 4;      // first owned unit
  const short* Ut = UtAll + (size_t)(dir * 3 + layer) * 768 * 256;
  const float* brc = brcAll + (dir * 3 + layer) * 768;

  // stage h-gate U^T rows [512,768) -> hgate, zero h buffers
  const short* Uth = Ut + 512 * 256;
  for (int c = tid; c < 8192; c += 1024) {
    int row = c >> 5, q = c & 31;
    *(uint4*)(hgate + row * HB_STRIDE + q * 8) = *(const uint4*)(Uth + row * 256 + q * 8);
  }
  for (int i = tid; i < 2 * HBLK; i += 1024) hbuf[i] = 0;

  // resident z/r A-fragments: lane (col,quad) holds A[m=col][k=quad*8+j]
  // = U^T[wave*16+col][ks*32+quad*8+j]
  short8 zA[8], rA[8];
#pragma unroll
  for (int ks = 0; ks < 8; ++ks) {
    zA[ks] = *(const short8*)(Ut + (size_t)(wave * 16 + col) * 256 + ks * 32 + quad * 8);
    rA[ks] = *(const short8*)(Ut + (size_t)(256 + wave * 16 + col) * 256 + ks * 32 + quad * 8);
  }
  f32x4 brh;
#pragma unroll
  for (int r = 0; r < 4; ++r) brh[r] = brc[512 + u0 + r];

  // xp addressing (bytes): base = ((t*2+dir)*64 + b)*1536 + u0-within-dir*2
  //   z at +0, r at +512, h at +1024 (imm offsets)
  const int t0 = dir ? 511 : 0;
  const int tstep = dir ? -1 : 1;
  const char* xpb = (const char*)xp;
  const int gb = b0 + col;                  // global batch row for this thread
  unsigned xaddr = (unsigned)(((t0 * 2 + dir) * 64 + gb) * 1536 + wave * 32 + quad * 8);
  const int xstep = tstep * 196608;         // 2*64*1536

  // LDS lane offsets (halves)
  const short* hgA = hgate + (wave * 16 + col) * HB_STRIDE + quad * 8;
  const int rd_lane = col * HB_STRIDE + quad * 8;
  const int wr_lane = col * HB_STRIDE + u0;

  // y addressing (bytes): (t*64+b)*1024 + dir*512 + u0*2
  unsigned yoff = (unsigned)((t0 * 64 + gb) * 1024 + dir * 512 + u0 * 2);
  const int ystep = tstep * 65536;
  int moff = t0 * 64 + gb;

  // prologue prefetch for s=0
  uint2 pz, pr, ph;
  unsigned pm;
  pz = *(const uint2*)(xpb + xaddr);
  pr = *(const uint2*)(xpb + xaddr + 512);
  ph = *(const uint2*)(xpb + xaddr + 1024);
  pm = maskt[moff];

  float hp[4] = {0.f, 0.f, 0.f, 0.f};
  __syncthreads();

  for (int s = 0; s < 512; ++s) {
    // init accumulators from prefetched projections (z,r) and recur bias (h)
    f32x4 az, ar, ah;
    az[0] = cvt_lo(pz.x); az[1] = cvt_hi(pz.x);
    az[2] = cvt_lo(pz.y); az[3] = cvt_hi(pz.y);
    ar[0] = cvt_lo(pr.x); ar[1] = cvt_hi(pr.x);
    ar[2] = cvt_lo(pr.y); ar[3] = cvt_hi(pr.y);
    ah = brh;
    float xh[4];
    xh[0] = cvt_lo(ph.x); xh[1] = cvt_hi(ph.x);
    xh[2] = cvt_lo(ph.y); xh[3] = cvt_hi(ph.y);
    const bool mv = (pm != 0u);
    // issue next-step prefetch (consumed at next init)
    if (s < 511) {
      xaddr += xstep;
      pz = *(const uint2*)(xpb + xaddr);
      pr = *(const uint2*)(xpb + xaddr + 512);
      ph = *(const uint2*)(xpb + xaddr + 1024);
      moff += tstep * 64;
      pm = maskt[moff];
    }

    // recurrent matmul: A=U^T (z/r regs, h LDS), B=h(t-1) from LDS
    const short* hrd = hbuf + (s & 1) * HBLK + rd_lane;
#pragma unroll
    for (int ks = 0; ks < 8; ++ks) {
      short8 hbv = *(const short8*)(hrd + ks * 32);
      short8 hg  = *(const short8*)(hgA + ks * 32);
      az = __builtin_amdgcn_mfma_f32_16x16x32_bf16(zA[ks], hbv, az, 0, 0, 0);
      ar = __builtin_amdgcn_mfma_f32_16x16x32_bf16(rA[ks], hbv, ar, 0, 0, 0);
      ah = __builtin_amdgcn_mfma_f32_16x16x32_bf16(hg,     hbv, ah, 0, 0, 0);
    }

    // epilogue: 4 consecutive units for one batch row
    float hn[4];
#pragma unroll
    for (int r = 0; r < 4; ++r) {
      float z  = 1.f / (1.f + __builtin_amdgcn_exp2f(az[r] * -1.44269504f));
      float rr = 1.f / (1.f + __builtin_amdgcn_exp2f(ar[r] * -1.44269504f));
      float pre = xh[r] + rr * ah[r];
      float hc = 1.f - 2.f / (__builtin_amdgcn_exp2f(pre * 2.88539008f) + 1.f);
      float hpv = hp[r];
      float v = hc + z * (hpv - hc);
      hn[r] = mv ? v : hpv;
      hp[r] = hn[r];
    }
    uint2 packed;
    asm("v_cvt_pk_bf16_f32 %0, %1, %2" : "=v"(packed.x) : "v"(hn[0]), "v"(hn[1]));
    asm("v_cvt_pk_bf16_f32 %0, %1, %2" : "=v"(packed.y) : "v"(hn[2]), "v"(hn[3]));
    *(uint2*)(hbuf + ((s & 1) ^ 1) * HBLK + wr_lane) = packed;
    *(uint2*)((char*)yout + yoff) = packed;
    yoff += ystep;
    // LDS-only barrier (no vmcnt drain): global ops stay in flight
    LDS_BARRIER();
  }
}

// ---- dropout (JAX threefry partitionable); j == gid (t-major) ----
__global__ __launch_bounds__(256) void drop_k(
    short* __restrict__ xb16, float* __restrict__ dout,
    const int* __restrict__ training, unsigned k0, unsigned k1, int last) {
  const unsigned gid = blockIdx.x * 256 + threadIdx.x;
  float v = bf2f(xb16[gid]);
  unsigned y0, y1;
  tf2x32(k0, k1, 0u, gid, &y0, &y1);
  unsigned bits = y0 ^ y1;
  float u = __uint_as_float((bits >> 9) | 0x3f800000u) - 1.0f;
  bool keep = u < 0.9f;
  int tr = *training;
  float ov = tr ? (keep ? v * (1.0f / 0.9f) : 0.0f) : v;
  if (last) {
    unsigned r = gid >> 9, c = gid & 511u;
    unsigned t = r >> 6, b = r & 63u;
    dout[(size_t)(b * 512 + t) * 512 + c] = ov;
  } else {
    xb16[gid] = f2bf(ov);
  }
}

extern "C" void kernel_launch(void* const* d_in, const int* in_sizes, int n_in,
                              void* d_out, int out_size, void* d_ws, size_t ws_size,
                              hipStream_t stream) {
  (void)in_sizes; (void)n_in; (void)out_size; (void)ws_size;
  const float* states = (const float*)d_in[0];
  const void*  mask   = d_in[1];
  const int*   training = (const int*)d_in[3];
  const float* Wf = (const float*)d_in[4];
  const float* Uf = (const float*)d_in[5];
  const float* bf_ = (const float*)d_in[6];
  const float* Wb = (const float*)d_in[7];
  const float* Ub = (const float*)d_in[8];
  const float* bb_ = (const float*)d_in[9];
  char* ws = (char*)d_ws;

  short* xb16   = (short*)(ws + XB16_OFF);
  _Float16* xp  = (_Float16*)(ws + XP_OFF);
  short* Wt     = (short*)(ws + WT_OFF);
  short* Ut     = (short*)(ws + UT_OFF);
  float* biasc  = (float*)(ws + BIASC_OFF);
  float* brc    = (float*)(ws + BRC_OFF);
  unsigned char* maskt = (unsigned char*)(ws + MASKT_OFF);
  unsigned* flag = (unsigned*)(ws + FLAG_OFF);
  float* dout = (float*)d_out;

  // allow >64KB dynamic LDS for gru16 (idempotent; not a stream op)
  hipFuncSetAttribute((const void*)gru16,
                      hipFuncAttributeMaxDynamicSharedMemorySize, (int)LDS_BYTES);

  // threefry key chain: key(1234); per layer: dkey,sk = split(dkey)
  unsigned d0 = 0u, d1 = 1234u, sk0[3], sk1[3];
  for (int l = 0; l < 3; ++l) {
    unsigned a, b, c, d;
    tf2x32(d0, d1, 0u, 0u, &a, &b);   // new dkey
    tf2x32(d0, d1, 0u, 1u, &c, &d);   // subkey
    sk0[l] = c; sk1[l] = d;
    d0 = a; d1 = b;
  }

  init_k<<<1, 64, 0, stream>>>(flag);
  prep_k<<<65536, 256, 0, stream>>>(states, (const unsigned*)mask, Wf, Uf, bf_,
                                    Wb, Ub, bb_, xb16, dout, Wt, Ut, biasc, brc, flag);
  maskt_k<<<128, 256, 0, stream>>>((const unsigned char*)mask, flag, maskt);
  for (int l = 0; l < 3; ++l) {
    proj_gemm<<<dim3(256, 12), 256, 0, stream>>>(xb16, Wt + (size_t)l * 1536 * 512,
                                                 biasc + l * 1536, xp);
    gru16<<<8, 1024, LDS_BYTES, stream>>>(xp, Ut, brc, maskt, xb16, l);
    drop_k<<<65536, 256, 0, stream>>>(xb16, dout, training, sk0[l], sk1[l], l == 2);
  }
}